// Round 12
// baseline (6247.068 us; speedup 1.0000x reference)
//
#include <hip/hip_runtime.h>

#define DEVINL __device__ __forceinline__

DEVINL float lrelu(float v) { return v >= 0.f ? v : 0.01f * v; }

// ---------------------------------------------------------------------------
// oneDNN-order conv1d v4: T_TILE=256 (8 t/thread), O_TILE=64 (8 o/thread).
// Per output element ONE sequential fmaf chain, nest (icb16, kw, ic16) with
// i = iq*4+ii ascending — bit-identical to v3 per element.
// Division-free staging; xsT[parity][pos][i16] rows (stride 20, 16B aligned);
// w in LDS [o][k][i16], loaded per (k,iq) as broadcast float4s.
// 256 thr = 32 tt x 8 tg; t = t0 + tt + 32a (a<8), o = ob + tg*8 + j (j<8).
// ---------------------------------------------------------------------------
template<int CIN, int COUT, int K, int S, int P, bool ACT, int LIN, int LOUT>
__global__ __launch_bounds__(256) void conv_dnn4(const float* __restrict__ x,
                                                 const float* __restrict__ w,
                                                 const float* __restrict__ bias,
                                                 float* __restrict__ y)
{
    constexpr int T_TILE = 256;
    constexpr int SPAN = (T_TILE - 1) * S + K;
    constexpr int PH   = (S == 2) ? (SPAN / 2 + 1) : SPAN;
    constexpr int RS   = 20;
    constexpr int NPAR = (S == 2) ? 2 : 1;

    __shared__ float xsT[NPAR][PH][RS];
    __shared__ float wsT[64 * K * 16];

    const int tid = threadIdx.x;
    const int tt  = tid & 31;
    const int tg  = tid >> 5;
    const int t0  = blockIdx.x * T_TILE;
    const int ob  = blockIdx.y * 64;
    const int b   = blockIdx.z;
    const int x0  = t0 * S - P;

    float acc[8][8];
#pragma unroll
    for (int j = 0; j < 8; ++j)
#pragma unroll
        for (int a = 0; a < 8; ++a) acc[j][a] = 0.f;

    const float* xb = x + (size_t)b * CIN * LIN;

    for (int cb = 0; cb < CIN / 16; ++cb) {
        __syncthreads();
        // x staging: division-free, coalesced global dword reads
#pragma unroll
        for (int i = 0; i < 16; ++i) {
            const float* xr = xb + (size_t)(cb * 16 + i) * LIN;
            for (int s = tid; s < SPAN; s += 256) {
                int g = x0 + s;
                float v = (g >= 0 && g < LIN) ? xr[g] : 0.f;
                if constexpr (S == 2) xsT[s & 1][s >> 1][i] = v;
                else                  xsT[0][s][i] = v;
            }
        }
        // w staging: pow2 index split (o = idx>>4, i = idx&15), loop over k
#pragma unroll
        for (int k = 0; k < K; ++k) {
            for (int idx = tid; idx < 64 * 16; idx += 256) {
                int o = idx >> 4, i = idx & 15;
                wsT[(o * K + k) * 16 + i] = w[((size_t)(ob + o) * CIN + cb * 16 + i) * K + k];
            }
        }
        __syncthreads();

#pragma unroll
        for (int k = 0; k < K; ++k) {
#pragma unroll
            for (int iq = 0; iq < 4; ++iq) {
                float wr8[8][4];
#pragma unroll
                for (int j = 0; j < 8; ++j) {
                    float4 t = *(const float4*)&wsT[((tg * 8 + j) * K + k) * 16 + iq * 4];
                    wr8[j][0]=t.x; wr8[j][1]=t.y; wr8[j][2]=t.z; wr8[j][3]=t.w;
                }
#pragma unroll
                for (int ah = 0; ah < 2; ++ah) {       // split a to bound live xq regs
                    float xq[4][4];
#pragma unroll
                    for (int al = 0; al < 4; ++al) {
                        const int a = ah * 4 + al;
                        const int s = (tt + 32 * a) * S + k;
                        const float* row;
                        if constexpr (S == 2) row = &xsT[s & 1][s >> 1][0];
                        else                  row = &xsT[0][s][0];
                        float4 t = *(const float4*)&row[iq * 4];
                        xq[al][0]=t.x; xq[al][1]=t.y; xq[al][2]=t.z; xq[al][3]=t.w;
                    }
#pragma unroll
                    for (int j = 0; j < 8; ++j)
#pragma unroll
                        for (int al = 0; al < 4; ++al)
#pragma unroll
                            for (int ii = 0; ii < 4; ++ii)   // i = iq*4+ii ascending
                                acc[j][ah * 4 + al] = fmaf(xq[al][ii], wr8[j][ii], acc[j][ah * 4 + al]);
                }
            }
        }
    }

#pragma unroll
    for (int j = 0; j < 8; ++j) {
        const int o = ob + tg * 8 + j;
        const float bv = bias[o];
#pragma unroll
        for (int a = 0; a < 8; ++a) {
            float r = acc[j][a] + bv;
            if (ACT) r = lrelu(r);
            y[((size_t)b * COUT + o) * LOUT + t0 + tt + 32 * a] = r;
        }
    }
}

// ---------------------------------------------------------------------------
// E1 oneDNN order: CIN=2 zero-padded block: chain (kw, ic in {0,1}).
// ---------------------------------------------------------------------------
__global__ __launch_bounds__(256) void e1_dnn(const float* __restrict__ x,
                                              const float* __restrict__ w1,
                                              const float* __restrict__ b1,
                                              float* __restrict__ y)
{
    const int tid = threadIdx.x;
    const int t0  = blockIdx.x * 1024 + tid * 4;
    const int o   = blockIdx.y;
    const int b   = blockIdx.z;

    float wr[2][4];
#pragma unroll
    for (int i = 0; i < 2; ++i)
#pragma unroll
        for (int k = 0; k < 4; ++k) wr[i][k] = w1[(o * 2 + i) * 4 + k];
    const float bv = b1[o];

    float acc[4] = {0.f, 0.f, 0.f, 0.f};
#pragma unroll
    for (int k = 0; k < 4; ++k)          // kw outer
#pragma unroll
        for (int i = 0; i < 2; ++i) {    // ic inner
            const float* xb = x + ((size_t)b * 2 + i) * 8192;
#pragma unroll
            for (int a = 0; a < 4; ++a) {
                int p = (t0 + a) * 2 - 1 + k;
                float v = (p >= 0 && p < 8192) ? xb[p] : 0.f;
                acc[a] = fmaf(v, wr[i][k], acc[a]);
            }
        }
    float4 r;
    r.x = lrelu(acc[0] + bv); r.y = lrelu(acc[1] + bv);
    r.z = lrelu(acc[2] + bv); r.w = lrelu(acc[3] + bv);
    *(float4*)&y[((size_t)b * 128 + o) * 4096 + t0] = r;
}

// ---------------------------------------------------------------------------
// Codebook prep + VQ (unchanged — picks verified).
// ---------------------------------------------------------------------------
__global__ void cbt_kernel(const float* __restrict__ cb, float* __restrict__ cbT)
{
    int idx = blockIdx.x * 256 + threadIdx.x;
    if (idx < 512 * 64) {
        int k = idx >> 6, d = idx & 63;
        cbT[d * 512 + k] = cb[idx];
    }
}

__global__ void norms_kernel(const float* __restrict__ cb, float* __restrict__ norms)
{
#pragma clang fp contract(off)
    int k = blockIdx.x * 256 + threadIdx.x;
    if (k < 512) {
        float s = 0.f;
        for (int d = 0; d < 64; ++d) {
            float c = cb[k * 64 + d];
            float sq = c * c;
            s = s + sq;
        }
        norms[k] = s;
    }
}

__global__ __launch_bounds__(256) void vq_exact(const float* __restrict__ qin,
                                                const float* __restrict__ cb,
                                                const float* __restrict__ cbT,
                                                const float* __restrict__ norms,
                                                float* __restrict__ st,
                                                double* __restrict__ lacc)
{
#pragma clang fp contract(off)
    __shared__ double wsum[4];
    const int tid  = threadIdx.x;
    const int lane = tid & 63;
    const int wv   = tid >> 6;
    const size_t n = (size_t)blockIdx.x * 4 + wv;

    const float qv = qin[n * 64 + lane];

    float A = 0.f;
    for (int d = 0; d < 64; ++d) {
        float qd = __shfl(qv, d);
        float sq = qd * qd;
        A = A + sq;
    }

    float AB[8] = {0.f,0.f,0.f,0.f,0.f,0.f,0.f,0.f};
    for (int d = 0; d < 64; ++d) {
        float qd = __shfl(qv, d);
#pragma unroll
        for (int r = 0; r < 8; ++r) {
            float c = cbT[d * 512 + r * 64 + lane];
            AB[r] = fmaf(qd, c, AB[r]);
        }
    }

    float bd = 1e30f;
    int   bk = 0x7fffffff;
#pragma unroll
    for (int r = 0; r < 8; ++r) {
        int k = r * 64 + lane;
        float t1 = A + norms[k];
        float c2 = 2.f * AB[r];
        float dk = t1 - c2;
        if (dk < bd) { bd = dk; bk = k; }
    }
#pragma unroll
    for (int off = 32; off > 0; off >>= 1) {
        float od = __shfl_down(bd, off);
        int   ok = __shfl_down(bk, off);
        if (od < bd || (od == bd && ok < bk)) { bd = od; bk = ok; }
    }
    const int kb = __shfl(bk, 0);

    const float c   = cb[(size_t)kb * 64 + lane];
    const float dif = c - qv;
    const float stv = qv + dif;
    st[n * 64 + lane] = stv;
    float sq = dif * dif;
    double part = (double)sq;
#pragma unroll
    for (int off = 32; off > 0; off >>= 1) part += __shfl_down(part, off);
    if (lane == 0) wsum[wv] = part;
    __syncthreads();
    if (tid == 0) atomicAdd(lacc, wsum[0] + wsum[1] + wsum[2] + wsum[3]);
}

__global__ void zero_kernel(double* __restrict__ p) { p[0] = 0.0; }

__global__ void finalize_kernel(const double* __restrict__ acc, float* __restrict__ out)
{
    out[0] = (float)(1.25 * (acc[0] / 4194304.0));
}

// ---------------------------------------------------------------------------
// FAST fp32 decoder (unchanged this round).
// ---------------------------------------------------------------------------
template<int CIN, int COUT, int K, int STRIDE, int PAD, bool ACT, int LIN, int LOUT, int CI_CHUNK, int WT>
__global__ __launch_bounds__(256) void conv_kernel(const float* __restrict__ x,
                                                   const float* __restrict__ w,
                                                   const float* __restrict__ bias,
                                                   float* __restrict__ y)
{
    constexpr int SPAN  = 127 * STRIDE + K;
    constexpr int SPANP = ((SPAN + 11) & ~3);
    constexpr int NEED  = 3 * STRIDE + K;
    constexpr int NV    = (NEED + 3) / 4;
    constexpr int KP    = (K >= 3) ? 4 : K;

    __shared__ float xs[CI_CHUNK][SPANP];
    __shared__ float ws[32][CI_CHUNK][KP];

    const int tid = threadIdx.x;
    const int tt  = tid & 31;
    const int tg  = tid >> 5;
    const int t0  = blockIdx.x * 128;
    const int ob  = blockIdx.y * 32;
    const int b   = blockIdx.z;

    float acc[4][4];
#pragma unroll
    for (int j = 0; j < 4; ++j) { acc[j][0]=0.f; acc[j][1]=0.f; acc[j][2]=0.f; acc[j][3]=0.f; }

    const float* xb = x + (size_t)b * CIN * LIN;
    const int x0 = t0 * STRIDE - PAD;

    for (int ci = 0; ci < CIN; ci += CI_CHUNK) {
        for (int idx = tid; idx < CI_CHUNK * SPAN; idx += 256) {
            int i = idx / SPAN, s = idx - i * SPAN;
            int tin = x0 + s;
            xs[i][s] = (tin >= 0 && tin < LIN) ? xb[(size_t)(ci + i) * LIN + tin] : 0.f;
        }
        for (int idx = tid; idx < 32 * CI_CHUNK * K; idx += 256) {
            int o = idx / (CI_CHUNK * K);
            int rem = idx - o * (CI_CHUNK * K);
            int i = rem / K, k = rem - i * K;
            if constexpr (WT == 0)
                ws[o][i][k] = w[((size_t)(ob + o) * CIN + (ci + i)) * K + k];
            else
                ws[o][i][k] = w[((size_t)(ci + i) * COUT + (ob + o)) * K + (K - 1 - k)];
        }
        __syncthreads();

#pragma unroll 4
        for (int i = 0; i < CI_CHUNK; ++i) {
            float xv[NV * 4];
#pragma unroll
            for (int v = 0; v < NV; ++v) {
                float4 t = *(const float4*)&xs[i][tt * 4 * STRIDE + 4 * v];
                xv[4*v+0]=t.x; xv[4*v+1]=t.y; xv[4*v+2]=t.z; xv[4*v+3]=t.w;
            }
#pragma unroll
            for (int j = 0; j < 4; ++j) {
                float wv[KP];
                if constexpr (KP == 4) {
                    float4 t = *(const float4*)&ws[tg*4+j][i][0];
                    wv[0]=t.x; wv[1]=t.y; wv[2]=t.z; wv[3]=t.w;
                } else {
                    wv[0] = ws[tg*4+j][i][0];
                    if constexpr (KP >= 2) wv[1] = ws[tg*4+j][i][1];
                }
#pragma unroll
                for (int a = 0; a < 4; ++a)
#pragma unroll
                    for (int k = 0; k < K; ++k)
                        acc[j][a] += xv[a * STRIDE + k] * wv[k];
            }
        }
        __syncthreads();
    }

#pragma unroll
    for (int j = 0; j < 4; ++j) {
        const int o = ob + tg * 4 + j;
        const float bv = bias[o];
        float4 r;
        r.x = acc[j][0] + bv; r.y = acc[j][1] + bv; r.z = acc[j][2] + bv; r.w = acc[j][3] + bv;
        if constexpr (ACT) { r.x=lrelu(r.x); r.y=lrelu(r.y); r.z=lrelu(r.z); r.w=lrelu(r.w); }
        *(float4*)&y[((size_t)b * COUT + o) * LOUT + t0 + 4 * tt] = r;
    }
}

template<int CIN, int COUT, int LIN, int CI_CHUNK>
__global__ __launch_bounds__(256) void convt_kernel(const float* __restrict__ x,
                                                    const float* __restrict__ w,
                                                    const float* __restrict__ bias,
                                                    float* __restrict__ y)
{
    constexpr int LOUT = 2 * LIN;
    constexpr int SPAN = 67, SPANP = 72;
    __shared__ float xs[CI_CHUNK][SPANP];
    __shared__ float ws[32][CI_CHUNK][4];

    const int tid = threadIdx.x;
    const int tt  = tid & 31;
    const int tg  = tid >> 5;
    const int t0  = blockIdx.x * 128;
    const int mb  = t0 >> 1;
    const int ob  = blockIdx.y * 32;
    const int b   = blockIdx.z;

    float acc[4][4];
#pragma unroll
    for (int j = 0; j < 4; ++j) { acc[j][0]=0.f; acc[j][1]=0.f; acc[j][2]=0.f; acc[j][3]=0.f; }

    const float* xb = x + (size_t)b * CIN * LIN;

    for (int ci = 0; ci < CIN; ci += CI_CHUNK) {
        for (int idx = tid; idx < CI_CHUNK * SPAN; idx += 256) {
            int i = idx / SPAN, s = idx - i * SPAN;
            int m = mb - 1 + s;
            xs[i][s] = (m >= 0 && m < LIN) ? xb[(size_t)(ci + i) * LIN + m] : 0.f;
        }
        for (int idx = tid; idx < 32 * CI_CHUNK * 4; idx += 256) {
            int o = idx / (CI_CHUNK * 4);
            int rem = idx - o * (CI_CHUNK * 4);
            int i = rem >> 2, k = rem & 3;
            ws[o][i][k] = w[((size_t)(ci + i) * COUT + (ob + o)) * 4 + k];
        }
        __syncthreads();

#pragma unroll 4
        for (int i = 0; i < CI_CHUNK; ++i) {
            float2 p0 = *(const float2*)&xs[i][2 * tt];
            float2 p1 = *(const float2*)&xs[i][2 * tt + 2];
            const float a0 = p0.x, a1 = p0.y, a2 = p1.x, a3 = p1.y;
#pragma unroll
            for (int j = 0; j < 4; ++j) {
                float4 wv = *(const float4*)&ws[tg*4+j][i][0];
                acc[j][0] += a1 * wv.y + a0 * wv.w;
                acc[j][1] += a2 * wv.x + a1 * wv.z;
                acc[j][2] += a2 * wv.y + a1 * wv.w;
                acc[j][3] += a3 * wv.x + a2 * wv.z;
            }
        }
        __syncthreads();
    }

#pragma unroll
    for (int j = 0; j < 4; ++j) {
        const int o = ob + tg * 4 + j;
        const float bv = bias[o];
        float4 r;
        r.x = lrelu(acc[j][0] + bv); r.y = lrelu(acc[j][1] + bv);
        r.z = lrelu(acc[j][2] + bv); r.w = lrelu(acc[j][3] + bv);
        *(float4*)&y[((size_t)b * COUT + o) * LOUT + t0 + 4 * tt] = r;
    }
}

__global__ __launch_bounds__(256) void d5_kernel(const float* __restrict__ x,
                                                 const float* __restrict__ w,
                                                 const float* __restrict__ bias,
                                                 float* __restrict__ y)
{
    constexpr int CIN = 128, LIN = 4096, LOUT = 8192, CI_CHUNK = 16;
    constexpr int SPAN = 515, SPANP = 520;
    __shared__ float xs[CI_CHUNK][SPANP];
    __shared__ float wsm[2][CIN][4];
    __shared__ float bsm[2];

    const int tid = threadIdx.x;
    const int t0  = blockIdx.x * 1024;
    const int mb  = t0 >> 1;
    const int b   = blockIdx.y;

    for (int idx = tid; idx < 1024; idx += 256) {
        int k = idx & 3, t = idx >> 2;
        int i = t & 127, o = t >> 7;
        wsm[o][i][k] = w[((size_t)i * 2 + o) * 4 + k];
    }
    if (tid < 2) bsm[tid] = bias[tid];

    float acc[2][4] = {{0.f,0.f,0.f,0.f},{0.f,0.f,0.f,0.f}};
    const float* xb = x + (size_t)b * CIN * LIN;

    for (int ci = 0; ci < CIN; ci += CI_CHUNK) {
        for (int idx = tid; idx < CI_CHUNK * SPAN; idx += 256) {
            int i = idx / SPAN, s = idx - i * SPAN;
            int m = mb - 1 + s;
            xs[i][s] = (m >= 0 && m < LIN) ? xb[(size_t)(ci + i) * LIN + m] : 0.f;
        }
        __syncthreads();
#pragma unroll 4
        for (int i = 0; i < CI_CHUNK; ++i) {
            float2 p0 = *(const float2*)&xs[i][2 * tid];
            float2 p1 = *(const float2*)&xs[i][2 * tid + 2];
            const float a0 = p0.x, a1 = p0.y, a2 = p1.x, a3 = p1.y;
#pragma unroll
            for (int o = 0; o < 2; ++o) {
                float4 wv = *(const float4*)&wsm[o][ci + i][0];
                acc[o][0] += a1 * wv.y + a0 * wv.w;
                acc[o][1] += a2 * wv.x + a1 * wv.z;
                acc[o][2] += a2 * wv.y + a1 * wv.w;
                acc[o][3] += a3 * wv.x + a2 * wv.z;
            }
        }
        __syncthreads();
    }
#pragma unroll
    for (int o = 0; o < 2; ++o) {
        float4 r;
        r.x = acc[o][0] + bsm[o]; r.y = acc[o][1] + bsm[o];
        r.z = acc[o][2] + bsm[o]; r.w = acc[o][3] + bsm[o];
        *(float4*)&y[((size_t)b * 2 + o) * LOUT + t0 + 4 * tid] = r;
    }
}

// ---------------------------------------------------------------------------
// Workspace identical to R11 (peak ~168 MB, proven safe).
// ---------------------------------------------------------------------------
extern "C" void kernel_launch(void* const* d_in, const int* in_sizes, int n_in,
                              void* d_out, int out_size, void* d_ws, size_t ws_size,
                              hipStream_t stream)
{
    const float* x   = (const float*)d_in[0];
    const float* w1  = (const float*)d_in[1];  const float* b1  = (const float*)d_in[2];
    const float* w2  = (const float*)d_in[3];  const float* b2  = (const float*)d_in[4];
    const float* w3  = (const float*)d_in[5];  const float* b3  = (const float*)d_in[6];
    const float* w4  = (const float*)d_in[7];  const float* b4  = (const float*)d_in[8];
    const float* w5  = (const float*)d_in[9];  const float* b5  = (const float*)d_in[10];
    const float* qw  = (const float*)d_in[11]; const float* qb  = (const float*)d_in[12];
    const float* cbk = (const float*)d_in[13];
    const float* dw1 = (const float*)d_in[14]; const float* db1 = (const float*)d_in[15];
    const float* dw2 = (const float*)d_in[16]; const float* db2 = (const float*)d_in[17];
    const float* dw3 = (const float*)d_in[18]; const float* db3 = (const float*)d_in[19];
    const float* dw4 = (const float*)d_in[20]; const float* db4 = (const float*)d_in[21];
    const float* dw5 = (const float*)d_in[22]; const float* db5 = (const float*)d_in[23];

    float* wsf   = (float*)d_ws;
    float* A     = wsf;
    float* Bb    = wsf + 16777216;
    float* C     = wsf + 33554432;
    float* cbT   = wsf + 41943040;
    float* norms = wsf + 41975808;
    double* lacc = (double*)(wsf + 41976320);

    float* h4  = A;
    float* h5  = A + 8388608;
    float* qin = A + 10485760;
    float* st  = A + 12582912;

    cbt_kernel<<<128, 256, 0, stream>>>(cbk, cbT);
    norms_kernel<<<2, 256, 0, stream>>>(cbk, norms);
    zero_kernel<<<1, 1, 0, stream>>>(lacc);

    constexpr int BS = 32;
    for (int s = 0; s < 2; ++s) {
        const float* xs   = x + (size_t)s * BS * 2 * 8192;
        float*       decs = (float*)d_out + (size_t)s * BS * 2 * 8192;

        // ---- encoder: oneDNN-order fp32 fmaf chains (icb16, kw, ic16) ----
        e1_dnn<<<dim3(4, 128, BS), 256, 0, stream>>>(xs, w1, b1, A);                               // h1
        conv_dnn4<128,256,4,2,1,true,4096,2048><<<dim3(8,4,BS),256,0,stream>>>(A,  w2, b2, Bb);    // h2
        conv_dnn4<256,256,4,2,1,true,2048,1024><<<dim3(4,4,BS),256,0,stream>>>(Bb, w3, b3, C);     // h3
        conv_dnn4<256,256,3,1,1,true,1024,1024><<<dim3(4,4,BS),256,0,stream>>>(C,  w4, b4, h4);    // h4
        conv_dnn4<256,64,1,1,0,true,1024,1024><<<dim3(4,1,BS),256,0,stream>>>(h4, w5, b5, h5);     // h5
        conv_dnn4<64,64,1,1,0,false,1024,1024><<<dim3(4,1,BS),256,0,stream>>>(h5, qw, qb, qin);    // q_in

        // ---- fp32 VQ ----
        vq_exact<<<8192, 256, 0, stream>>>(qin, cbk, cbT, norms, st, lacc);

        // ---- fast fp32 decoder ----
        conv_kernel<64,256,1,1,0,true,1024,1024,32,1><<<dim3(8,8,BS),256,0,stream>>>(st, dw1, db1, Bb); // g1
        conv_kernel<256,256,3,1,1,true,1024,1024,32,1><<<dim3(8,8,BS),256,0,stream>>>(Bb, dw2, db2, C); // g2
        convt_kernel<256,256,1024,32><<<dim3(16,8,BS),256,0,stream>>>(C, dw3, db3, Bb);                 // g3
        convt_kernel<256,128,2048,32><<<dim3(32,4,BS),256,0,stream>>>(Bb, dw4, db4, A);                 // g4
        d5_kernel<<<dim3(8, BS), 256, 0, stream>>>(A, dw5, db5, decs);                                  // dec
    }

    finalize_kernel<<<1, 1, 0, stream>>>(lacc, (float*)d_out + 1048576);
}

// Round 13
// 4846.449 us; speedup vs baseline: 1.2890x; 1.2890x over previous
//
#include <hip/hip_runtime.h>

#define DEVINL __device__ __forceinline__

DEVINL float lrelu(float v) { return v >= 0.f ? v : 0.01f * v; }

// ---------------------------------------------------------------------------
// Repack conv weights [COUT][CIN][K] -> wq[cb][k][iq][og][o16*4+ii]
// so each (cb,k,iq,og) slice is 64 contiguous floats (wave-uniform s_load).
// ---------------------------------------------------------------------------
template<int CIN, int COUT, int K>
__global__ __launch_bounds__(256) void repack_w(const float* __restrict__ w,
                                                float* __restrict__ wq)
{
    int f = blockIdx.x * 256 + threadIdx.x;
    if (f >= CIN * COUT * K) return;
    constexpr int NOG = COUT / 16;
    int ii   = f & 3;
    int o16  = (f >> 2) & 15;
    int rest = f >> 6;
    int og   = rest % NOG;
    int r2   = rest / NOG;
    int iq   = r2 & 3;
    int r3   = r2 >> 2;
    int k    = r3 % K;
    int cb   = r3 / K;
    int o = og * 16 + o16;
    int i = cb * 16 + iq * 4 + ii;
    wq[f] = w[((size_t)o * CIN + i) * K + k];
}

// ---------------------------------------------------------------------------
// oneDNN-order conv1d v5: wave-owns-16-outputs, w via wave-uniform scalar
// loads (no LDS w traffic), XOR-swizzled x LDS (conflict-free b128 reads).
// Per output element ONE sequential fmaf chain, nest (icb16, kw, ic16) with
// i = iq*4+ii ascending — bit-identical to v3 per element.
// Block 256 = 4 waves; wave wid handles o = (by*4+wid)*16 + o16 (o16<16);
// lane l handles t = t0 + l + 64a (a<2), T_TILE=128.
// ---------------------------------------------------------------------------
template<int CIN, int COUT, int K, int S, int P, bool ACT, int LIN, int LOUT>
__global__ __launch_bounds__(256) void conv_dnn5(const float* __restrict__ x,
                                                 const float* __restrict__ wq,
                                                 const float* __restrict__ bias,
                                                 float* __restrict__ y)
{
    constexpr int T_TILE = 128;
    constexpr int SPAN = (T_TILE - 1) * S + K;
    constexpr int PH   = (S == 2) ? (SPAN / 2 + 1) : SPAN;
    constexpr int RS   = 20;
    constexpr int NPAR = (S == 2) ? 2 : 1;
    constexpr int NOG  = COUT / 16;

    __shared__ float xsT[NPAR][PH][RS];

    const int tid  = threadIdx.x;
    const int lane = tid & 63;
    const int wid  = __builtin_amdgcn_readfirstlane(tid >> 6);
    const int t0   = blockIdx.x * T_TILE;
    const int ogg  = blockIdx.y * 4 + wid;
    const int b    = blockIdx.z;
    const int x0   = t0 * S - P;

    float acc[16][2];
#pragma unroll
    for (int o16 = 0; o16 < 16; ++o16) { acc[o16][0] = 0.f; acc[o16][1] = 0.f; }

    const float* xb = x + (size_t)b * CIN * LIN;

    for (int cb = 0; cb < CIN / 16; ++cb) {
        __syncthreads();
        for (int idx = tid; idx < 16 * SPAN; idx += 256) {
            int i = idx / SPAN, s = idx - i * SPAN;
            int g = x0 + s;
            float v = (g >= 0 && g < LIN) ? xb[(size_t)(cb * 16 + i) * LIN + g] : 0.f;
            int u   = (S == 2) ? (s >> 1) : s;
            int par = (S == 2) ? (s & 1) : 0;
            int c = (((i >> 2) ^ ((u >> 3) & 3)) << 2) | (i & 3);
            xsT[par][u][c] = v;
        }
        __syncthreads();

#pragma unroll
        for (int k = 0; k < K; ++k) {
#pragma unroll
            for (int iq = 0; iq < 4; ++iq) {
                float xq[2][4];
#pragma unroll
                for (int a = 0; a < 2; ++a) {
                    int s = (lane + 64 * a) * S + k;
                    int u   = (S == 2) ? (s >> 1) : s;
                    int par = (S == 2) ? (s & 1) : 0;
                    int col = ((iq ^ ((u >> 3) & 3)) << 2);
                    float4 t = *(const float4*)&xsT[par][u][col];
                    xq[a][0] = t.x; xq[a][1] = t.y; xq[a][2] = t.z; xq[a][3] = t.w;
                }
                const float* wp = wq + ((((size_t)cb * K + k) * 4 + iq) * NOG + ogg) * 64;
#pragma unroll
                for (int o16 = 0; o16 < 16; ++o16) {
                    float4 wv = *(const float4*)&wp[o16 * 4];
#pragma unroll
                    for (int a = 0; a < 2; ++a) {
                        acc[o16][a] = fmaf(xq[a][0], wv.x, acc[o16][a]);
                        acc[o16][a] = fmaf(xq[a][1], wv.y, acc[o16][a]);
                        acc[o16][a] = fmaf(xq[a][2], wv.z, acc[o16][a]);
                        acc[o16][a] = fmaf(xq[a][3], wv.w, acc[o16][a]);
                    }
                }
            }
        }
    }

#pragma unroll
    for (int o16 = 0; o16 < 16; ++o16) {
        const int o = ogg * 16 + o16;
        const float bv = bias[o];
#pragma unroll
        for (int a = 0; a < 2; ++a) {
            float r = acc[o16][a] + bv;
            if (ACT) r = lrelu(r);
            y[((size_t)b * COUT + o) * LOUT + t0 + lane + 64 * a] = r;
        }
    }
}

// ---------------------------------------------------------------------------
// E1 oneDNN order: CIN=2 zero-padded block: chain (kw, ic in {0,1}).
// ---------------------------------------------------------------------------
__global__ __launch_bounds__(256) void e1_dnn(const float* __restrict__ x,
                                              const float* __restrict__ w1,
                                              const float* __restrict__ b1,
                                              float* __restrict__ y)
{
    const int tid = threadIdx.x;
    const int t0  = blockIdx.x * 1024 + tid * 4;
    const int o   = blockIdx.y;
    const int b   = blockIdx.z;

    float wr[2][4];
#pragma unroll
    for (int i = 0; i < 2; ++i)
#pragma unroll
        for (int k = 0; k < 4; ++k) wr[i][k] = w1[(o * 2 + i) * 4 + k];
    const float bv = b1[o];

    float acc[4] = {0.f, 0.f, 0.f, 0.f};
#pragma unroll
    for (int k = 0; k < 4; ++k)          // kw outer
#pragma unroll
        for (int i = 0; i < 2; ++i) {    // ic inner
            const float* xb = x + ((size_t)b * 2 + i) * 8192;
#pragma unroll
            for (int a = 0; a < 4; ++a) {
                int p = (t0 + a) * 2 - 1 + k;
                float v = (p >= 0 && p < 8192) ? xb[p] : 0.f;
                acc[a] = fmaf(v, wr[i][k], acc[a]);
            }
        }
    float4 r;
    r.x = lrelu(acc[0] + bv); r.y = lrelu(acc[1] + bv);
    r.z = lrelu(acc[2] + bv); r.w = lrelu(acc[3] + bv);
    *(float4*)&y[((size_t)b * 128 + o) * 4096 + t0] = r;
}

// ---------------------------------------------------------------------------
// Codebook prep + VQ (unchanged — picks verified).
// ---------------------------------------------------------------------------
__global__ void cbt_kernel(const float* __restrict__ cb, float* __restrict__ cbT)
{
    int idx = blockIdx.x * 256 + threadIdx.x;
    if (idx < 512 * 64) {
        int k = idx >> 6, d = idx & 63;
        cbT[d * 512 + k] = cb[idx];
    }
}

__global__ void norms_kernel(const float* __restrict__ cb, float* __restrict__ norms)
{
#pragma clang fp contract(off)
    int k = blockIdx.x * 256 + threadIdx.x;
    if (k < 512) {
        float s = 0.f;
        for (int d = 0; d < 64; ++d) {
            float c = cb[k * 64 + d];
            float sq = c * c;
            s = s + sq;
        }
        norms[k] = s;
    }
}

__global__ __launch_bounds__(256) void vq_exact(const float* __restrict__ qin,
                                                const float* __restrict__ cb,
                                                const float* __restrict__ cbT,
                                                const float* __restrict__ norms,
                                                float* __restrict__ st,
                                                double* __restrict__ lacc)
{
#pragma clang fp contract(off)
    __shared__ double wsum[4];
    const int tid  = threadIdx.x;
    const int lane = tid & 63;
    const int wv   = tid >> 6;
    const size_t n = (size_t)blockIdx.x * 4 + wv;

    const float qv = qin[n * 64 + lane];

    float A = 0.f;
    for (int d = 0; d < 64; ++d) {
        float qd = __shfl(qv, d);
        float sq = qd * qd;
        A = A + sq;
    }

    float AB[8] = {0.f,0.f,0.f,0.f,0.f,0.f,0.f,0.f};
    for (int d = 0; d < 64; ++d) {
        float qd = __shfl(qv, d);
#pragma unroll
        for (int r = 0; r < 8; ++r) {
            float c = cbT[d * 512 + r * 64 + lane];
            AB[r] = fmaf(qd, c, AB[r]);
        }
    }

    float bd = 1e30f;
    int   bk = 0x7fffffff;
#pragma unroll
    for (int r = 0; r < 8; ++r) {
        int k = r * 64 + lane;
        float t1 = A + norms[k];
        float c2 = 2.f * AB[r];
        float dk = t1 - c2;
        if (dk < bd) { bd = dk; bk = k; }
    }
#pragma unroll
    for (int off = 32; off > 0; off >>= 1) {
        float od = __shfl_down(bd, off);
        int   ok = __shfl_down(bk, off);
        if (od < bd || (od == bd && ok < bk)) { bd = od; bk = ok; }
    }
    const int kb = __shfl(bk, 0);

    const float c   = cb[(size_t)kb * 64 + lane];
    const float dif = c - qv;
    const float stv = qv + dif;
    st[n * 64 + lane] = stv;
    float sq = dif * dif;
    double part = (double)sq;
#pragma unroll
    for (int off = 32; off > 0; off >>= 1) part += __shfl_down(part, off);
    if (lane == 0) wsum[wv] = part;
    __syncthreads();
    if (tid == 0) atomicAdd(lacc, wsum[0] + wsum[1] + wsum[2] + wsum[3]);
}

__global__ void zero_kernel(double* __restrict__ p) { p[0] = 0.0; }

__global__ void finalize_kernel(const double* __restrict__ acc, float* __restrict__ out)
{
    out[0] = (float)(1.25 * (acc[0] / 4194304.0));
}

// ---------------------------------------------------------------------------
// FAST fp32 decoder (R11 versions, unchanged).
// ---------------------------------------------------------------------------
template<int CIN, int COUT, int K, int STRIDE, int PAD, bool ACT, int LIN, int LOUT, int CI_CHUNK, int WT>
__global__ __launch_bounds__(256) void conv_kernel(const float* __restrict__ x,
                                                   const float* __restrict__ w,
                                                   const float* __restrict__ bias,
                                                   float* __restrict__ y)
{
    constexpr int SPAN  = 127 * STRIDE + K;
    constexpr int SPANP = ((SPAN + 11) & ~3);
    constexpr int NEED  = 3 * STRIDE + K;
    constexpr int NV    = (NEED + 3) / 4;
    constexpr int KP    = (K >= 3) ? 4 : K;

    __shared__ float xs[CI_CHUNK][SPANP];
    __shared__ float ws[32][CI_CHUNK][KP];

    const int tid = threadIdx.x;
    const int tt  = tid & 31;
    const int tg  = tid >> 5;
    const int t0  = blockIdx.x * 128;
    const int ob  = blockIdx.y * 32;
    const int b   = blockIdx.z;

    float acc[4][4];
#pragma unroll
    for (int j = 0; j < 4; ++j) { acc[j][0]=0.f; acc[j][1]=0.f; acc[j][2]=0.f; acc[j][3]=0.f; }

    const float* xb = x + (size_t)b * CIN * LIN;
    const int x0 = t0 * STRIDE - PAD;

    for (int ci = 0; ci < CIN; ci += CI_CHUNK) {
        for (int idx = tid; idx < CI_CHUNK * SPAN; idx += 256) {
            int i = idx / SPAN, s = idx - i * SPAN;
            int tin = x0 + s;
            xs[i][s] = (tin >= 0 && tin < LIN) ? xb[(size_t)(ci + i) * LIN + tin] : 0.f;
        }
        for (int idx = tid; idx < 32 * CI_CHUNK * K; idx += 256) {
            int o = idx / (CI_CHUNK * K);
            int rem = idx - o * (CI_CHUNK * K);
            int i = rem / K, k = rem - i * K;
            if constexpr (WT == 0)
                ws[o][i][k] = w[((size_t)(ob + o) * CIN + (ci + i)) * K + k];
            else
                ws[o][i][k] = w[((size_t)(ci + i) * COUT + (ob + o)) * K + (K - 1 - k)];
        }
        __syncthreads();

#pragma unroll 4
        for (int i = 0; i < CI_CHUNK; ++i) {
            float xv[NV * 4];
#pragma unroll
            for (int v = 0; v < NV; ++v) {
                float4 t = *(const float4*)&xs[i][tt * 4 * STRIDE + 4 * v];
                xv[4*v+0]=t.x; xv[4*v+1]=t.y; xv[4*v+2]=t.z; xv[4*v+3]=t.w;
            }
#pragma unroll
            for (int j = 0; j < 4; ++j) {
                float wv[KP];
                if constexpr (KP == 4) {
                    float4 t = *(const float4*)&ws[tg*4+j][i][0];
                    wv[0]=t.x; wv[1]=t.y; wv[2]=t.z; wv[3]=t.w;
                } else {
                    wv[0] = ws[tg*4+j][i][0];
                    if constexpr (KP >= 2) wv[1] = ws[tg*4+j][i][1];
                }
#pragma unroll
                for (int a = 0; a < 4; ++a)
#pragma unroll
                    for (int k = 0; k < K; ++k)
                        acc[j][a] += xv[a * STRIDE + k] * wv[k];
            }
        }
        __syncthreads();
    }

#pragma unroll
    for (int j = 0; j < 4; ++j) {
        const int o = ob + tg * 4 + j;
        const float bv = bias[o];
        float4 r;
        r.x = acc[j][0] + bv; r.y = acc[j][1] + bv; r.z = acc[j][2] + bv; r.w = acc[j][3] + bv;
        if constexpr (ACT) { r.x=lrelu(r.x); r.y=lrelu(r.y); r.z=lrelu(r.z); r.w=lrelu(r.w); }
        *(float4*)&y[((size_t)b * COUT + o) * LOUT + t0 + 4 * tt] = r;
    }
}

template<int CIN, int COUT, int LIN, int CI_CHUNK>
__global__ __launch_bounds__(256) void convt_kernel(const float* __restrict__ x,
                                                    const float* __restrict__ w,
                                                    const float* __restrict__ bias,
                                                    float* __restrict__ y)
{
    constexpr int LOUT = 2 * LIN;
    constexpr int SPAN = 67, SPANP = 72;
    __shared__ float xs[CI_CHUNK][SPANP];
    __shared__ float ws[32][CI_CHUNK][4];

    const int tid = threadIdx.x;
    const int tt  = tid & 31;
    const int tg  = tid >> 5;
    const int t0  = blockIdx.x * 128;
    const int mb  = t0 >> 1;
    const int ob  = blockIdx.y * 32;
    const int b   = blockIdx.z;

    float acc[4][4];
#pragma unroll
    for (int j = 0; j < 4; ++j) { acc[j][0]=0.f; acc[j][1]=0.f; acc[j][2]=0.f; acc[j][3]=0.f; }

    const float* xb = x + (size_t)b * CIN * LIN;

    for (int ci = 0; ci < CIN; ci += CI_CHUNK) {
        for (int idx = tid; idx < CI_CHUNK * SPAN; idx += 256) {
            int i = idx / SPAN, s = idx - i * SPAN;
            int m = mb - 1 + s;
            xs[i][s] = (m >= 0 && m < LIN) ? xb[(size_t)(ci + i) * LIN + m] : 0.f;
        }
        for (int idx = tid; idx < 32 * CI_CHUNK * 4; idx += 256) {
            int o = idx / (CI_CHUNK * 4);
            int rem = idx - o * (CI_CHUNK * 4);
            int i = rem >> 2, k = rem & 3;
            ws[o][i][k] = w[((size_t)(ci + i) * COUT + (ob + o)) * 4 + k];
        }
        __syncthreads();

#pragma unroll 4
        for (int i = 0; i < CI_CHUNK; ++i) {
            float2 p0 = *(const float2*)&xs[i][2 * tt];
            float2 p1 = *(const float2*)&xs[i][2 * tt + 2];
            const float a0 = p0.x, a1 = p0.y, a2 = p1.x, a3 = p1.y;
#pragma unroll
            for (int j = 0; j < 4; ++j) {
                float4 wv = *(const float4*)&ws[tg*4+j][i][0];
                acc[j][0] += a1 * wv.y + a0 * wv.w;
                acc[j][1] += a2 * wv.x + a1 * wv.z;
                acc[j][2] += a2 * wv.y + a1 * wv.w;
                acc[j][3] += a3 * wv.x + a2 * wv.z;
            }
        }
        __syncthreads();
    }

#pragma unroll
    for (int j = 0; j < 4; ++j) {
        const int o = ob + tg * 4 + j;
        const float bv = bias[o];
        float4 r;
        r.x = lrelu(acc[j][0] + bv); r.y = lrelu(acc[j][1] + bv);
        r.z = lrelu(acc[j][2] + bv); r.w = lrelu(acc[j][3] + bv);
        *(float4*)&y[((size_t)b * COUT + o) * LOUT + t0 + 4 * tt] = r;
    }
}

__global__ __launch_bounds__(256) void d5_kernel(const float* __restrict__ x,
                                                 const float* __restrict__ w,
                                                 const float* __restrict__ bias,
                                                 float* __restrict__ y)
{
    constexpr int CIN = 128, LIN = 4096, LOUT = 8192, CI_CHUNK = 16;
    constexpr int SPAN = 515, SPANP = 520;
    __shared__ float xs[CI_CHUNK][SPANP];
    __shared__ float wsm[2][CIN][4];
    __shared__ float bsm[2];

    const int tid = threadIdx.x;
    const int t0  = blockIdx.x * 1024;
    const int mb  = t0 >> 1;
    const int b   = blockIdx.y;

    for (int idx = tid; idx < 1024; idx += 256) {
        int k = idx & 3, t = idx >> 2;
        int i = t & 127, o = t >> 7;
        wsm[o][i][k] = w[((size_t)i * 2 + o) * 4 + k];
    }
    if (tid < 2) bsm[tid] = bias[tid];

    float acc[2][4] = {{0.f,0.f,0.f,0.f},{0.f,0.f,0.f,0.f}};
    const float* xb = x + (size_t)b * CIN * LIN;

    for (int ci = 0; ci < CIN; ci += CI_CHUNK) {
        for (int idx = tid; idx < CI_CHUNK * SPAN; idx += 256) {
            int i = idx / SPAN, s = idx - i * SPAN;
            int m = mb - 1 + s;
            xs[i][s] = (m >= 0 && m < LIN) ? xb[(size_t)(ci + i) * LIN + m] : 0.f;
        }
        __syncthreads();
#pragma unroll 4
        for (int i = 0; i < CI_CHUNK; ++i) {
            float2 p0 = *(const float2*)&xs[i][2 * tid];
            float2 p1 = *(const float2*)&xs[i][2 * tid + 2];
            const float a0 = p0.x, a1 = p0.y, a2 = p1.x, a3 = p1.y;
#pragma unroll
            for (int o = 0; o < 2; ++o) {
                float4 wv = *(const float4*)&wsm[o][ci + i][0];
                acc[o][0] += a1 * wv.y + a0 * wv.w;
                acc[o][1] += a2 * wv.x + a1 * wv.z;
                acc[o][2] += a2 * wv.y + a1 * wv.w;
                acc[o][3] += a3 * wv.x + a2 * wv.z;
            }
        }
        __syncthreads();
    }
#pragma unroll
    for (int o = 0; o < 2; ++o) {
        float4 r;
        r.x = acc[o][0] + bsm[o]; r.y = acc[o][1] + bsm[o];
        r.z = acc[o][2] + bsm[o]; r.w = acc[o][3] + bsm[o];
        *(float4*)&y[((size_t)b * 2 + o) * LOUT + t0 + 4 * tid] = r;
    }
}

// ---------------------------------------------------------------------------
// Workspace (floats), peak ~170.4 MB (ws >= 192 MB proven safe):
//   A 0 | Bb 16777216 | C 33554432 | cbT 41943040 | norms 41975808
//   lacc 41976320 (f64) | wq2 41976336 (131072) | wq3 42107408 (262144)
//   wq4 42369552 (196608) | wq5 42566160 (16384) | wqq 42582544 (4096)
// ---------------------------------------------------------------------------
extern "C" void kernel_launch(void* const* d_in, const int* in_sizes, int n_in,
                              void* d_out, int out_size, void* d_ws, size_t ws_size,
                              hipStream_t stream)
{
    const float* x   = (const float*)d_in[0];
    const float* w1  = (const float*)d_in[1];  const float* b1  = (const float*)d_in[2];
    const float* w2  = (const float*)d_in[3];  const float* b2  = (const float*)d_in[4];
    const float* w3  = (const float*)d_in[5];  const float* b3  = (const float*)d_in[6];
    const float* w4  = (const float*)d_in[7];  const float* b4  = (const float*)d_in[8];
    const float* w5  = (const float*)d_in[9];  const float* b5  = (const float*)d_in[10];
    const float* qw  = (const float*)d_in[11]; const float* qb  = (const float*)d_in[12];
    const float* cbk = (const float*)d_in[13];
    const float* dw1 = (const float*)d_in[14]; const float* db1 = (const float*)d_in[15];
    const float* dw2 = (const float*)d_in[16]; const float* db2 = (const float*)d_in[17];
    const float* dw3 = (const float*)d_in[18]; const float* db3 = (const float*)d_in[19];
    const float* dw4 = (const float*)d_in[20]; const float* db4 = (const float*)d_in[21];
    const float* dw5 = (const float*)d_in[22]; const float* db5 = (const float*)d_in[23];

    float* wsf   = (float*)d_ws;
    float* A     = wsf;
    float* Bb    = wsf + 16777216;
    float* C     = wsf + 33554432;
    float* cbT   = wsf + 41943040;
    float* norms = wsf + 41975808;
    double* lacc = (double*)(wsf + 41976320);
    float* wq2   = wsf + 41976336;
    float* wq3   = wsf + 42107408;
    float* wq4   = wsf + 42369552;
    float* wq5   = wsf + 42566160;
    float* wqq   = wsf + 42582544;

    float* h4  = A;
    float* h5  = A + 8388608;
    float* qin = A + 10485760;
    float* st  = A + 12582912;

    cbt_kernel<<<128, 256, 0, stream>>>(cbk, cbT);
    norms_kernel<<<2, 256, 0, stream>>>(cbk, norms);
    zero_kernel<<<1, 1, 0, stream>>>(lacc);
    repack_w<128, 256, 4><<<512, 256, 0, stream>>>(w2, wq2);
    repack_w<256, 256, 4><<<1024, 256, 0, stream>>>(w3, wq3);
    repack_w<256, 256, 3><<<768, 256, 0, stream>>>(w4, wq4);
    repack_w<256, 64, 1><<<64, 256, 0, stream>>>(w5, wq5);
    repack_w<64, 64, 1><<<16, 256, 0, stream>>>(qw, wqq);

    constexpr int BS = 32;
    for (int s = 0; s < 2; ++s) {
        const float* xs   = x + (size_t)s * BS * 2 * 8192;
        float*       decs = (float*)d_out + (size_t)s * BS * 2 * 8192;

        // ---- encoder: oneDNN-order fp32 fmaf chains (icb16, kw, ic16) ----
        e1_dnn<<<dim3(4, 128, BS), 256, 0, stream>>>(xs, w1, b1, A);                               // h1
        conv_dnn5<128,256,4,2,1,true,4096,2048><<<dim3(16,4,BS),256,0,stream>>>(A,  wq2, b2, Bb);  // h2
        conv_dnn5<256,256,4,2,1,true,2048,1024><<<dim3(8,4,BS),256,0,stream>>>(Bb, wq3, b3, C);    // h3
        conv_dnn5<256,256,3,1,1,true,1024,1024><<<dim3(8,4,BS),256,0,stream>>>(C,  wq4, b4, h4);   // h4
        conv_dnn5<256,64,1,1,0,true,1024,1024><<<dim3(8,1,BS),256,0,stream>>>(h4, wq5, b5, h5);    // h5
        conv_dnn5<64,64,1,1,0,false,1024,1024><<<dim3(8,1,BS),256,0,stream>>>(h5, wqq, qb, qin);   // q_in

        // ---- fp32 VQ ----
        vq_exact<<<8192, 256, 0, stream>>>(qin, cbk, cbT, norms, st, lacc);

        // ---- fast fp32 decoder ----
        conv_kernel<64,256,1,1,0,true,1024,1024,32,1><<<dim3(8,8,BS),256,0,stream>>>(st, dw1, db1, Bb); // g1
        conv_kernel<256,256,3,1,1,true,1024,1024,32,1><<<dim3(8,8,BS),256,0,stream>>>(Bb, dw2, db2, C); // g2
        convt_kernel<256,256,1024,32><<<dim3(16,8,BS),256,0,stream>>>(C, dw3, db3, Bb);                 // g3
        convt_kernel<256,128,2048,32><<<dim3(32,4,BS),256,0,stream>>>(Bb, dw4, db4, A);                 // g4
        d5_kernel<<<dim3(8, BS), 256, 0, stream>>>(A, dw5, db5, decs);                                  // dec
    }

    finalize_kernel<<<1, 1, 0, stream>>>(lacc, (float*)d_out + 1048576);
}